// Round 11
// baseline (475.310 us; speedup 1.0000x reference)
//
#include <hip/hip_runtime.h>

#define NN 50000     // nodes
#define NE 800000    // edges
#define DD 64        // channels
#define NG 512       // graphs
#define NL 5         // layers

// ---------------- CSR build (by dst) ----------------

__global__ void count_deg_k(const int* __restrict__ dst, int* __restrict__ deg) {
    int e = blockIdx.x * blockDim.x + threadIdx.x;
    if (e < NE) atomicAdd(&deg[dst[e]], 1);
}

// start[i] = exclusive prefix of deg, allocated via one atomic per wave
__global__ void calc_start_k(const int* __restrict__ deg, int* __restrict__ start,
                             int* __restrict__ cursor) {
    int i = blockIdx.x * blockDim.x + threadIdx.x;
    int lane = threadIdx.x & 63;
    int d = (i < NN) ? deg[i] : 0;
    int incl = d;
#pragma unroll
    for (int off = 1; off < 64; off <<= 1) {
        int t = __shfl_up(incl, off, 64);
        if (lane >= off) incl += t;
    }
    int total = __shfl(incl, 63, 64);
    int base = 0;
    if (lane == 0 && total > 0) base = atomicAdd(cursor, total);
    base = __shfl(base, 0, 64);
    if (i < NN) start[i] = base + incl - d;
}

// nt-store on the scattered col write: avoid cross-XCD dirty-line churn
// (R10: WRITE_SIZE 54.7 MB for a 3.2 MB array).
__global__ void fill_col_k(const int* __restrict__ src, const int* __restrict__ dst,
                           const int* __restrict__ start, int* __restrict__ fcnt,
                           int* __restrict__ col) {
    int e = blockIdx.x * blockDim.x + threadIdx.x;
    if (e < NE) {
        int d = dst[e];
        int p = atomicAdd(&fcnt[d], 1);
        __builtin_nontemporal_store(src[e], &col[start[d] + p]);
    }
}

// ---------------- aggregation v6: 2 nodes/wave, 32-edge chunks ----------------
// lanes = 4 edge-groups x 16 channel-quads. Per iteration: 2 col loads
// (one per node) + up to 16 independent float4 gathers in flight before the
// first use. Avg degree 16 -> typical wave does ONE iteration with 2 col +
// 8 gathers outstanding (v5 had 1 col + 4) — attacks exposed latency, the
// R9/R10-confirmed limiter. All chunk predicates are wave-uniform.
__global__ void aggregate_k(const float* __restrict__ h, const int* __restrict__ start,
                            const int* __restrict__ deg, const int* __restrict__ col,
                            float* __restrict__ agg) {
    int w2 = (blockIdx.x * blockDim.x + threadIdx.x) >> 6;   // node pair id
    int lane = threadIdx.x & 63;
    int n0 = w2 * 2;
    if (n0 >= NN) return;
    int n1 = n0 + 1;                   // NN even -> always valid
    int eg = lane >> 4;                // edge group 0..3
    int cl = lane & 15;                // channel quad
    int l31 = lane & 31;
    int s0 = start[n0], d0 = deg[n0];
    int s1 = start[n1], d1 = deg[n1];
    const float4* h4 = (const float4*)h;
    float4 A0 = {0,0,0,0}, A1 = {0,0,0,0};   // node0, two chains
    float4 B0 = {0,0,0,0}, B1 = {0,0,0,0};   // node1
    int dmax = max(d0, d1);
    for (int base = 0; base < dmax; base += 32) {
        int c0 = d0 - base, c1 = d1 - base;          // wave-uniform
        bool p0 = c0 > 0, h0 = c0 > 16;
        bool p1 = c1 > 0, h1 = c1 > 16;
        int cv0 = 0, cv1 = 0;
        if (p0) cv0 = col[s0 + ((base + l31 < d0) ? base + l31 : 0)];
        if (p1) cv1 = col[s1 + ((base + l31 < d1) ? base + l31 : 0)];
        float4 u0, u1, u2, u3, uu0, uu1, uu2, uu3;
        float4 v0, v1, v2, v3, vv0, vv1, vv2, vv3;
        if (p0) {
            int a0 = __shfl(cv0, eg + 0, 64),  a1 = __shfl(cv0, eg + 4, 64);
            int a2 = __shfl(cv0, eg + 8, 64),  a3 = __shfl(cv0, eg + 12, 64);
            u0 = h4[(size_t)a0 * 16 + cl]; u1 = h4[(size_t)a1 * 16 + cl];
            u2 = h4[(size_t)a2 * 16 + cl]; u3 = h4[(size_t)a3 * 16 + cl];
        }
        if (h0) {
            int a4 = __shfl(cv0, eg + 16, 64), a5 = __shfl(cv0, eg + 20, 64);
            int a6 = __shfl(cv0, eg + 24, 64), a7 = __shfl(cv0, eg + 28, 64);
            uu0 = h4[(size_t)a4 * 16 + cl]; uu1 = h4[(size_t)a5 * 16 + cl];
            uu2 = h4[(size_t)a6 * 16 + cl]; uu3 = h4[(size_t)a7 * 16 + cl];
        }
        if (p1) {
            int b0 = __shfl(cv1, eg + 0, 64),  b1 = __shfl(cv1, eg + 4, 64);
            int b2 = __shfl(cv1, eg + 8, 64),  b3 = __shfl(cv1, eg + 12, 64);
            v0 = h4[(size_t)b0 * 16 + cl]; v1 = h4[(size_t)b1 * 16 + cl];
            v2 = h4[(size_t)b2 * 16 + cl]; v3 = h4[(size_t)b3 * 16 + cl];
        }
        if (h1) {
            int b4 = __shfl(cv1, eg + 16, 64), b5 = __shfl(cv1, eg + 20, 64);
            int b6 = __shfl(cv1, eg + 24, 64), b7 = __shfl(cv1, eg + 28, 64);
            vv0 = h4[(size_t)b4 * 16 + cl]; vv1 = h4[(size_t)b5 * 16 + cl];
            vv2 = h4[(size_t)b6 * 16 + cl]; vv3 = h4[(size_t)b7 * 16 + cl];
        }
        if (p0) {
            if (eg + 0 < c0)  { A0.x += u0.x; A0.y += u0.y; A0.z += u0.z; A0.w += u0.w; }
            if (eg + 4 < c0)  { A1.x += u1.x; A1.y += u1.y; A1.z += u1.z; A1.w += u1.w; }
            if (eg + 8 < c0)  { A0.x += u2.x; A0.y += u2.y; A0.z += u2.z; A0.w += u2.w; }
            if (eg + 12 < c0) { A1.x += u3.x; A1.y += u3.y; A1.z += u3.z; A1.w += u3.w; }
        }
        if (h0) {
            if (eg + 16 < c0) { A0.x += uu0.x; A0.y += uu0.y; A0.z += uu0.z; A0.w += uu0.w; }
            if (eg + 20 < c0) { A1.x += uu1.x; A1.y += uu1.y; A1.z += uu1.z; A1.w += uu1.w; }
            if (eg + 24 < c0) { A0.x += uu2.x; A0.y += uu2.y; A0.z += uu2.z; A0.w += uu2.w; }
            if (eg + 28 < c0) { A1.x += uu3.x; A1.y += uu3.y; A1.z += uu3.z; A1.w += uu3.w; }
        }
        if (p1) {
            if (eg + 0 < c1)  { B0.x += v0.x; B0.y += v0.y; B0.z += v0.z; B0.w += v0.w; }
            if (eg + 4 < c1)  { B1.x += v1.x; B1.y += v1.y; B1.z += v1.z; B1.w += v1.w; }
            if (eg + 8 < c1)  { B0.x += v2.x; B0.y += v2.y; B0.z += v2.z; B0.w += v2.w; }
            if (eg + 12 < c1) { B1.x += v3.x; B1.y += v3.y; B1.z += v3.z; B1.w += v3.w; }
        }
        if (h1) {
            if (eg + 16 < c1) { B0.x += vv0.x; B0.y += vv0.y; B0.z += vv0.z; B0.w += vv0.w; }
            if (eg + 20 < c1) { B1.x += vv1.x; B1.y += vv1.y; B1.z += vv1.z; B1.w += vv1.w; }
            if (eg + 24 < c1) { B0.x += vv2.x; B0.y += vv2.y; B0.z += vv2.z; B0.w += vv2.w; }
            if (eg + 28 < c1) { B1.x += vv3.x; B1.y += vv3.y; B1.z += vv3.z; B1.w += vv3.w; }
        }
    }
    float4 A, B;
    A.x = A0.x + A1.x; A.y = A0.y + A1.y; A.z = A0.z + A1.z; A.w = A0.w + A1.w;
    B.x = B0.x + B1.x; B.y = B0.y + B1.y; B.z = B0.z + B1.z; B.w = B0.w + B1.w;
#pragma unroll
    for (int off = 16; off <= 32; off <<= 1) {
        A.x += __shfl_xor(A.x, off, 64); A.y += __shfl_xor(A.y, off, 64);
        A.z += __shfl_xor(A.z, off, 64); A.w += __shfl_xor(A.w, off, 64);
        B.x += __shfl_xor(B.x, off, 64); B.y += __shfl_xor(B.y, off, 64);
        B.z += __shfl_xor(B.z, off, 64); B.w += __shfl_xor(B.w, off, 64);
    }
    if (eg == 0) {
        ((float4*)(agg + (size_t)n0 * DD))[cl] = A;
        ((float4*)(agg + (size_t)n1 * DD))[cl] = B;
    }
}

// ---------------- dense layer v4 (proven R5/R7) ----------------
template <int RESID>
__global__ void __launch_bounds__(256, 3)
dense_layer_k(const float* __restrict__ agg, const float* __restrict__ hin,
              const float* __restrict__ wrel, const float* __restrict__ brel,
              const float* __restrict__ wroot, float* __restrict__ hout) {
    __shared__ float A[64][68];
    __shared__ float H[64][68];

    const int t = threadIdx.x;
    const int tile = blockIdx.x * 64;
    const int nrows = min(64, NN - tile);

    const float4* agg4 = (const float4*)(agg + (size_t)tile * DD);
    const float4* hin4 = (const float4*)(hin + (size_t)tile * DD);
#pragma unroll
    for (int k = 0; k < 4; ++k) {
        int idx = t + k * 256;
        int row = idx >> 4, cq = idx & 15;
        if (row < nrows) {
            *(float4*)&A[row][4 * cq] = agg4[idx];
            *(float4*)&H[row][4 * cq] = hin4[idx];
        }
    }
    __syncthreads();

    const int lane = t & 63;
    const int wv = __builtin_amdgcn_readfirstlane(t >> 6);
    const int o0 = wv * 16;

    float4 a4[8], h4[8];
    float acc[16];

#pragma unroll
    for (int cq = 0; cq < 8; ++cq) {
        a4[cq] = *(const float4*)&A[lane][4 * cq];
        h4[cq] = *(const float4*)&H[lane][4 * cq];
    }
#pragma unroll
    for (int oo = 0; oo < 16; ++oo) {
        int o = o0 + oo;
        const float* w1 = wrel + o * DD;
        const float* w2 = wroot + o * DD;
        float s0 = 0.f, s1 = 0.f, s2 = 0.f, s3 = 0.f;
#pragma unroll
        for (int cq = 0; cq < 8; ++cq) {
            s0 += a4[cq].x * w1[4 * cq + 0] + h4[cq].x * w2[4 * cq + 0];
            s1 += a4[cq].y * w1[4 * cq + 1] + h4[cq].y * w2[4 * cq + 1];
            s2 += a4[cq].z * w1[4 * cq + 2] + h4[cq].z * w2[4 * cq + 2];
            s3 += a4[cq].w * w1[4 * cq + 3] + h4[cq].w * w2[4 * cq + 3];
        }
        acc[oo] = (s0 + s1) + (s2 + s3);
    }

#pragma unroll
    for (int cq = 0; cq < 8; ++cq) {
        a4[cq] = *(const float4*)&A[lane][32 + 4 * cq];
        h4[cq] = *(const float4*)&H[lane][32 + 4 * cq];
    }
    __syncthreads();
    float* Out = &A[0][0];
#pragma unroll
    for (int oo = 0; oo < 16; ++oo) {
        int o = o0 + oo;
        const float* w1 = wrel + o * DD + 32;
        const float* w2 = wroot + o * DD + 32;
        float s0 = acc[oo], s1 = 0.f, s2 = 0.f, s3 = 0.f;
#pragma unroll
        for (int cq = 0; cq < 8; ++cq) {
            s0 += a4[cq].x * w1[4 * cq + 0] + h4[cq].x * w2[4 * cq + 0];
            s1 += a4[cq].y * w1[4 * cq + 1] + h4[cq].y * w2[4 * cq + 1];
            s2 += a4[cq].z * w1[4 * cq + 2] + h4[cq].z * w2[4 * cq + 2];
            s3 += a4[cq].w * w1[4 * cq + 3] + h4[cq].w * w2[4 * cq + 3];
        }
        Out[lane * 68 + o] = (s0 + s1) + (s2 + s3) + brel[o];
    }
    __syncthreads();

    float4* out4 = (float4*)(hout + (size_t)tile * DD);
#pragma unroll
    for (int k = 0; k < 4; ++k) {
        int idx = t + k * 256;
        int row = idx >> 4, cq = idx & 15;
        if (row < nrows) {
            float4 r = *(const float4*)&A[row][4 * cq];
            if (RESID) {
                float4 hr = *(const float4*)&H[row][4 * cq];
                r.x += hr.x; r.y += hr.y; r.z += hr.z; r.w += hr.w;
            }
            r.x = fmaxf(r.x, 0.f); r.y = fmaxf(r.y, 0.f);
            r.z = fmaxf(r.z, 0.f); r.w = fmaxf(r.w, 0.f);
            out4[idx] = r;
        }
    }
}

// ---------------- pooling (batch is sorted) ----------------

__global__ void pool_k(const float* __restrict__ h, const int* __restrict__ batch,
                       float* __restrict__ sums, int* __restrict__ cnt) {
    const int NP = 32;
    int w = (blockIdx.x * blockDim.x + threadIdx.x) >> 6;
    int lane = threadIdx.x & 63;
    int n0 = w * NP;
    if (n0 >= NN) return;
    int n1 = min(n0 + NP, NN);
    int g = batch[n0];
    float acc = 0.f;
    int run = 0;
    for (int i = n0; i < n1; ++i) {
        int gi = batch[i];
        if (gi != g) {
            atomicAdd(&sums[g * DD + lane], acc);
            if (lane == 0) atomicAdd(&cnt[g], run);
            acc = 0.f; run = 0; g = gi;
        }
        acc += h[i * DD + lane];
        run++;
    }
    atomicAdd(&sums[g * DD + lane], acc);
    if (lane == 0) atomicAdd(&cnt[g], run);
}

// ---------------- head: mean -> linear -> softmax ----------------

__global__ void head_k(const float* __restrict__ sums, const int* __restrict__ cnt,
                       const float* __restrict__ lin_w, const float* __restrict__ lin_b,
                       float* __restrict__ out) {
    int g = blockIdx.x * (blockDim.x >> 6) + (threadIdx.x >> 6);
    int o = threadIdx.x & 63;
    if (g >= NG) return;
    float c = (float)cnt[g];
    float inv = 1.0f / fmaxf(c, 1.0f);
    float acc = lin_b[o];
#pragma unroll 8
    for (int k = 0; k < DD; ++k) {
        acc += sums[g * DD + k] * inv * lin_w[o * DD + k];
    }
    float m = acc;
#pragma unroll
    for (int off = 32; off; off >>= 1) m = fmaxf(m, __shfl_xor(m, off, 64));
    float e = __expf(acc - m);
    float s = e;
#pragma unroll
    for (int off = 32; off; off >>= 1) s += __shfl_xor(s, off, 64);
    out[g * DD + o] = e / s;
}

// ---------------- driver ----------------

extern "C" void kernel_launch(void* const* d_in, const int* in_sizes, int n_in,
                              void* d_out, int out_size, void* d_ws, size_t ws_size,
                              hipStream_t stream) {
    const float* x      = (const float*)d_in[0];
    const int*   edge   = (const int*)d_in[1];   // [2, E]: src = edge, dst = edge+NE
    const int*   batch  = (const int*)d_in[2];
    const float* rel_w  = (const float*)d_in[3]; // [L, D, D]
    const float* rel_b  = (const float*)d_in[4]; // [L, D]
    const float* root_w = (const float*)d_in[5]; // [L, D, D]
    const float* lin_w  = (const float*)d_in[6]; // [D, D]
    const float* lin_b  = (const float*)d_in[7]; // [D]
    float* out = (float*)d_out;

    const int* src = edge;
    const int* dst = edge + NE;

    // workspace carve (all 256B aligned)
    char* p = (char*)d_ws;
    auto carve = [&](size_t bytes) {
        char* r = p;
        p += (bytes + 255) & ~(size_t)255;
        return (void*)r;
    };
    float* hA   = (float*)carve((size_t)NN * DD * 4);
    float* hB   = (float*)carve((size_t)NN * DD * 4);
    float* agg  = (float*)carve((size_t)NN * DD * 4);
    int*   col  = (int*)carve((size_t)NE * 4);
    int*   strt = (int*)carve((size_t)NN * 4);
    // ---- contiguous zero region (single memset) ----
    char* zbase = p;
    float* sums = (float*)carve((size_t)NG * DD * 4);
    int*   cnt  = (int*)carve((size_t)NG * 4);
    int*   deg  = (int*)carve((size_t)NN * 4);
    int*   fcnt = (int*)carve((size_t)NN * 4);
    int*   cur  = (int*)carve(4);
    size_t zbytes = (size_t)(p - zbase);

    hipMemsetAsync(zbase, 0, zbytes, stream);

    // CSR build
    count_deg_k<<<(NE + 255) / 256, 256, 0, stream>>>(dst, deg);
    calc_start_k<<<(NN + 255) / 256, 256, 0, stream>>>(deg, strt, cur);
    fill_col_k<<<(NE + 255) / 256, 256, 0, stream>>>(src, dst, strt, fcnt, col);

    const int aggBlocks = (NN / 2 + 3) / 4;  // 2 nodes per wave, 4 waves/block
    const int dnsBlocks = (NN + 63) / 64;    // 64 nodes per block

    // layer 0: x -> hA
    aggregate_k<<<aggBlocks, 256, 0, stream>>>(x, strt, deg, col, agg);
    dense_layer_k<0><<<dnsBlocks, 256, 0, stream>>>(agg, x, rel_w, rel_b, root_w, hA);
    // layer 1: hA -> hB
    aggregate_k<<<aggBlocks, 256, 0, stream>>>(hA, strt, deg, col, agg);
    dense_layer_k<0><<<dnsBlocks, 256, 0, stream>>>(agg, hA, rel_w + 4096, rel_b + 64,
                                                    root_w + 4096, hB);
    // layer 2: hB -> hA
    aggregate_k<<<aggBlocks, 256, 0, stream>>>(hB, strt, deg, col, agg);
    dense_layer_k<0><<<dnsBlocks, 256, 0, stream>>>(agg, hB, rel_w + 2 * 4096, rel_b + 2 * 64,
                                                    root_w + 2 * 4096, hA);
    // layer 3 (residual): hA -> hB
    aggregate_k<<<aggBlocks, 256, 0, stream>>>(hA, strt, deg, col, agg);
    dense_layer_k<1><<<dnsBlocks, 256, 0, stream>>>(agg, hA, rel_w + 3 * 4096, rel_b + 3 * 64,
                                                    root_w + 3 * 4096, hB);
    // layer 4 (residual): hB -> hA
    aggregate_k<<<aggBlocks, 256, 0, stream>>>(hB, strt, deg, col, agg);
    dense_layer_k<1><<<dnsBlocks, 256, 0, stream>>>(agg, hB, rel_w + 4 * 4096, rel_b + 4 * 64,
                                                    root_w + 4 * 4096, hA);

    // pool + head
    const int wavesPool = (NN + 31) / 32;
    pool_k<<<(wavesPool + 3) / 4, 256, 0, stream>>>(hA, batch, sums, cnt);
    head_k<<<(NG + 3) / 4, 256, 0, stream>>>(sums, cnt, lin_w, lin_b, out);
}